// Round 10
// baseline (452.194 us; speedup 1.0000x reference)
//
#include <hip/hip_runtime.h>

// Problem dims (fixed by the reference)
#define B_DIM 8192
#define N_DIM 1024
#define M_DIM 4096
#define A_DIM 1024
#define LN_EPS 1e-5f

typedef short s8v __attribute__((ext_vector_type(8)));      // 8x16-bit storage
typedef _Float16 h8v __attribute__((ext_vector_type(8)));   // 8 fp16 (4 VGPRs)
typedef float f4v __attribute__((ext_vector_type(4)));      // 4 fp32 acc
typedef unsigned short u16;

// fp32 -> fp16 (RTE). All values in this problem are O(1)-O(30), so fp16's
// 11 mantissa bits beat bf16's 8; range is irrelevant here.
__device__ __forceinline__ u16 f2h(float f) {
  union { _Float16 h; u16 u; } x; x.h = (_Float16)f; return x.u;
}
__device__ __forceinline__ float h2f(u16 u) {
  union { u16 u; _Float16 h; } x; x.u = u; return (float)x.h;
}

// async global->LDS, 16 B per lane. LDS dest = wave-uniform base + lane*16.
__device__ __forceinline__ void glds16(const void* g, void* l) {
  __builtin_amdgcn_global_load_lds(
      (const __attribute__((address_space(1))) unsigned int*)g,
      (__attribute__((address_space(3))) unsigned int*)l, 16, 0, 0);
}

// ---------------- merged prologue (one dispatch, block-uniform branch):
//   blocks [0,4096):    out_x = x ; xh = fp16(x)
//   blocks [4096,4608):  wqh = fp16(Wq)
//   blocks [4608,6656):  k = LN(relu(Wk)) -> kh ; v = LN(relu(Wv)) -> out_v+vh
//                        (wave-per-row, shfl_xor butterfly, no barriers)
#define NB_X 4096
#define NB_W 512
#define NB_KV 2048
__global__ __launch_bounds__(256) void prep_kernel(
    const float* __restrict__ x, float* __restrict__ outx, u16* __restrict__ xh,
    const float* __restrict__ wq, u16* __restrict__ wqh,
    const float* __restrict__ Wk, const float* __restrict__ Wv,
    const float* __restrict__ gk, const float* __restrict__ bk,
    const float* __restrict__ gv, const float* __restrict__ bv,
    u16* __restrict__ kh, float* __restrict__ outv, u16* __restrict__ vh) {
  const int b = blockIdx.x;
  if (b < NB_X + NB_W) {
    const bool isX = b < NB_X;
    const int i = (isX ? b : b - NB_X) * 256 + threadIdx.x;
    const float* src = (isX ? x : wq) + (size_t)i * 8;
    float4 v0 = *(const float4*)src;
    float4 v1 = *(const float4*)(src + 4);
    if (isX) {
      *(float4*)(outx + (size_t)i * 8) = v0;
      *(float4*)(outx + (size_t)i * 8 + 4) = v1;
    }
    const float f[8] = {v0.x, v0.y, v0.z, v0.w, v1.x, v1.y, v1.z, v1.w};
    s8v h;
#pragma unroll
    for (int j = 0; j < 8; j++) h[j] = (short)f2h(f[j]);
    *(s8v*)((isX ? xh : wqh) + (size_t)i * 8) = h;
    return;
  }
  // ---- KV relu+LN, wave-per-row
  const int gw = ((b - NB_X - NB_W) * 256 + threadIdx.x) >> 6;  // 0..8191
  const int l = threadIdx.x & 63;
  const bool isV = gw >= M_DIM;                                 // wave-uniform
  const int row = isV ? gw - M_DIM : gw;
  const float* pin = (isV ? Wv : Wk) + (size_t)row * 1024;
  const float* g = isV ? gv : gk;
  const float* bt = isV ? bv : bk;

  float4 v[4];
  float s = 0.f, ss = 0.f;
#pragma unroll
  for (int j = 0; j < 4; j++) {
    v[j] = *(const float4*)(pin + l * 4 + j * 256);
    v[j].x = fmaxf(v[j].x, 0.f); v[j].y = fmaxf(v[j].y, 0.f);
    v[j].z = fmaxf(v[j].z, 0.f); v[j].w = fmaxf(v[j].w, 0.f);
    s += v[j].x + v[j].y + v[j].z + v[j].w;
    ss += v[j].x * v[j].x + v[j].y * v[j].y + v[j].z * v[j].z + v[j].w * v[j].w;
  }
#pragma unroll
  for (int off = 1; off < 64; off <<= 1) {
    s += __shfl_xor(s, off, 64);
    ss += __shfl_xor(ss, off, 64);
  }
  const float mean = s * (1.f / 1024.f);
  const float var = ss * (1.f / 1024.f) - mean * mean;
  const float rs = rsqrtf(var + LN_EPS);

#pragma unroll
  for (int j = 0; j < 4; j++) {
    const float4 gg = *(const float4*)(g + l * 4 + j * 256);
    const float4 bb = *(const float4*)(bt + l * 4 + j * 256);
    float4 o;
    o.x = (v[j].x - mean) * rs * gg.x + bb.x;
    o.y = (v[j].y - mean) * rs * gg.y + bb.y;
    o.z = (v[j].z - mean) * rs * gg.z + bb.z;
    o.w = (v[j].w - mean) * rs * gg.w + bb.w;
    if (isV)
      *(float4*)(outv + (size_t)row * 1024 + l * 4 + j * 256) = o;
    ushort4 h;
    h.x = f2h(o.x); h.y = f2h(o.y); h.z = f2h(o.z); h.w = f2h(o.w);
    u16* oh = (isV ? vh : kh) + (size_t)row * 1024 + l * 4 + j * 256;
    *(ushort4*)oh = h;
  }
}

// ---------------- wave-per-row relu(+bias)+LN, fp16 input (q path), fp16 out.
__global__ __launch_bounds__(256) void relu_ln_q_kernel(
    const u16* __restrict__ in, const float* __restrict__ bias,
    const float* __restrict__ g, const float* __restrict__ bt,
    u16* __restrict__ outh) {
  const int row = (blockIdx.x * 256 + threadIdx.x) >> 6;
  const int l = threadIdx.x & 63;
  const u16* pin = in + (size_t)row * 1024;

  float e[16];
  float s = 0.f, ss = 0.f;
#pragma unroll
  for (int j = 0; j < 2; j++) {
    const h8v hv = *(const h8v*)(pin + l * 8 + j * 512);
    const float4 b0 = *(const float4*)(bias + l * 8 + j * 512);
    const float4 b1 = *(const float4*)(bias + l * 8 + j * 512 + 4);
    const float bb[8] = {b0.x, b0.y, b0.z, b0.w, b1.x, b1.y, b1.z, b1.w};
#pragma unroll
    for (int k = 0; k < 8; k++) {
      const float z = fmaxf((float)hv[k] + bb[k], 0.f);
      e[j * 8 + k] = z;
      s += z; ss += z * z;
    }
  }
#pragma unroll
  for (int off = 1; off < 64; off <<= 1) {
    s += __shfl_xor(s, off, 64);
    ss += __shfl_xor(ss, off, 64);
  }
  const float mean = s * (1.f / 1024.f);
  const float var = ss * (1.f / 1024.f) - mean * mean;
  const float rs = rsqrtf(var + LN_EPS);

#pragma unroll
  for (int j = 0; j < 2; j++) {
    const float4 g0 = *(const float4*)(g + l * 8 + j * 512);
    const float4 g1 = *(const float4*)(g + l * 8 + j * 512 + 4);
    const float4 t0 = *(const float4*)(bt + l * 8 + j * 512);
    const float4 t1 = *(const float4*)(bt + l * 8 + j * 512 + 4);
    const float gv_[8] = {g0.x, g0.y, g0.z, g0.w, g1.x, g1.y, g1.z, g1.w};
    const float tv[8] = {t0.x, t0.y, t0.z, t0.w, t1.x, t1.y, t1.z, t1.w};
    s8v h;
#pragma unroll
    for (int k = 0; k < 8; k++)
      h[k] = (short)f2h((e[j * 8 + k] - mean) * rs * gv_[k] + tv[k]);
    *(s8v*)(outh + (size_t)row * 1024 + l * 8 + j * 512) = h;
  }
}

// ------------------------------------------------- fp16 MFMA GEMM (nt)
// C[M_,N_] = A[M_,K] * B[N_,K]^T; A,B fp16 staged via glds.
// 128x128 tile, BK=32, DOUBLE-BUFFERED 2-phase: stage tile t+1 into buf^1
// BEFORE computing tile t; one __syncthreads per K-step (its vmcnt/lgkmcnt
// drain makes the rotation race-free: all waves' ds_reads of buf^1 and the
// t+1 stage loads complete before the barrier releases). Staging latency
// hides under the 16-MFMA compute. LDS 2x16.5 = 33 KB (4 blocks/CU, same
// occupancy as r9's BK=64). XCD-chunked blockIdx swizzle (nwg%8==0,
// bijective) gives A-panel L2 locality per XCD.
// OUTH==1: write fp16 (intermediate); else fp32.
// LDS rows: 32 fp16 = 4 chunks of 16 B; chunk c at slot c^((row>>1)&3)
// (2-way bank aliasing on ds_read_b128 = free; glds-compatible).
template <int OUTH>
__global__ __launch_bounds__(256) void gemm_mfma(const u16* __restrict__ AhG,
                                                 const u16* __restrict__ BhG,
                                                 void* __restrict__ Cv,
                                                 int N_, int K, int lda, int ldb) {
  __shared__ __align__(16) u16 Ah[2][128 * 32];
  __shared__ __align__(16) u16 Bh[2][128 * 32];

  const int t = threadIdx.x;
  const int lane = t & 63;
  const int wv = t >> 6;
  const int wm = (wv & 1) * 64;
  const int wn = (wv >> 1) * 64;

  // XCD-chunked swizzle: dispatch id d -> work id (d%8)*(nwg/8)+d/8
  const int gx = gridDim.x;
  const int nwg = gx * gridDim.y;
  int bid = blockIdx.y * gx + blockIdx.x;
  bid = (bid & 7) * (nwg >> 3) + (bid >> 3);
  const int m0 = (bid / gx) * 128;
  const int n0 = (bid % gx) * 128;

  // glds lane geometry: within a 16-row chunk, lane covers row=lane>>2, slot=lane&3
  const int ge = lane >> 2;
  const int gg = (lane & 3) ^ ((ge >> 1) & 3);  // global k-chunk to fetch

  // fragment geometry: lane reads row (lane&15), logical chunk (lane>>4)
  const int fr = lane & 15;
  const int fslot = (((lane >> 4) ^ ((fr >> 1) & 3))) * 8;

  f4v acc[4][4];
#pragma unroll
  for (int i = 0; i < 4; i++)
#pragma unroll
    for (int j = 0; j < 4; j++) acc[i][j] = (f4v)(0.f);

  // stage 32-k tile kt into buffer bf (4 glds per thread)
  auto stage = [&](int kt, int bf) {
#pragma unroll
    for (int h = 0; h < 2; h++) {
      const int c = wv * 2 + h;               // chunk 0..7
      const size_t aoff = (size_t)(m0 + c * 16 + ge) * lda + kt * 32 + gg * 8;
      const size_t boff = (size_t)(n0 + c * 16 + ge) * ldb + kt * 32 + gg * 8;
      glds16(AhG + aoff, &Ah[bf][c * 512]);
      glds16(BhG + boff, &Bh[bf][c * 512]);
    }
  };

  // compute one 32-k tile from buffer bf (8 ds_read_b128 + 16 MFMA)
  auto compute = [&](int bf) {
    h8v ah[4], bh[4];
#pragma unroll
    for (int i = 0; i < 4; i++) {
      ah[i] = *(const h8v*)&Ah[bf][(wm + i * 16 + fr) * 32 + fslot];
      bh[i] = *(const h8v*)&Bh[bf][(wn + i * 16 + fr) * 32 + fslot];
    }
#pragma unroll
    for (int i = 0; i < 4; i++)
#pragma unroll
      for (int j = 0; j < 4; j++)
        acc[i][j] = __builtin_amdgcn_mfma_f32_16x16x32_f16(ah[i], bh[j], acc[i][j], 0, 0, 0);
  };

  const int NT = K >> 5;
  stage(0, 0);
  __syncthreads();
  int cur = 0;
  for (int tt = 0; tt + 1 < NT; ++tt) {
    stage(tt + 1, cur ^ 1);   // prefetch next tile (overlaps with compute)
    compute(cur);
    __syncthreads();          // drains vm (stage) + lgkm (reads), then barrier
    cur ^= 1;
  }
  compute(cur);               // last tile; no barrier needed after

  // epilogue: C/D layout 16x16x32: col = lane&15, row = (lane>>4)*4 + reg
  const int cr = (lane >> 4) * 4;
  const int cc = lane & 15;
#pragma unroll
  for (int i = 0; i < 4; i++)
#pragma unroll
    for (int r = 0; r < 4; r++) {
      const size_t rowoff = (size_t)(m0 + wm + i * 16 + cr + r) * N_ + n0 + wn + cc;
      if constexpr (OUTH) {
        u16* cp = (u16*)Cv + rowoff;
#pragma unroll
        for (int j = 0; j < 4; j++) cp[j * 16] = f2h(acc[i][j][r]);
      } else {
        float* cp = (float*)Cv + rowoff;
#pragma unroll
        for (int j = 0; j < 4; j++) cp[j * 16] = acc[i][j][r];
      }
    }
}

// --------------------------------------- fused sparsemax + sparse x_hat = f @ v
// Exact sparsemax tau via fixed-point iteration tau <- (sum_{s>tau} s - 1)/cnt.
// Any fixed point satisfies sum (s - tau)_+ = 1 exactly (KKT), so it IS the
// reference tau. Init tau0 = max(s) - 1: since tau* >= max-1 (largest f <= 1),
// every iterate's threshold set remains a superset of the true support ->
// ~3-6 iterations. Max element always stays active -> cnt >= 1; cap 64 iters.
// Occupancy: u16 idx + fp16 w compact list -> 16.5 KB LDS -> 8 blocks/CU.
__global__ __launch_bounds__(256) void sparsemax_xhat_kernel(
    const u16* __restrict__ sh,    // [B,4096] fp16 raw scores
    float* __restrict__ fout,      // [B,4096] f output (fp32)
    const u16* __restrict__ vh,    // [4096,1024] fp16 v
    float* __restrict__ xhat,      // [B,1024]
    float scale) {
  __shared__ float sm[16];
  __shared__ u16 s_idx[4096];
  __shared__ u16 s_w[4096];
  __shared__ int s_cnt;
  const int row = blockIdx.x;
  const u16* p = sh + (size_t)row * 4096;
  float* fo = fout + (size_t)row * 4096;
  const int t = threadIdx.x;
  const int lane = t & 63;
  const int base = t * 16;   // 16 contiguous elems per thread (vectorized)

  h8v h0 = *(const h8v*)(p + base);
  h8v h1 = *(const h8v*)(p + base + 8);
  float s[16];
#pragma unroll
  for (int j = 0; j < 8; j++) {
    s[j] = (float)h0[j] * scale;
    s[j + 8] = (float)h1[j] * scale;
  }

  // block max -> tau0 = max - 1
  float mx = s[0];
#pragma unroll
  for (int j = 1; j < 16; j++) mx = fmaxf(mx, s[j]);
  {
#pragma unroll
    for (int off = 32; off > 0; off >>= 1) mx = fmaxf(mx, __shfl_down(mx, off, 64));
    const int wid = t >> 6;
    if (lane == 0) sm[wid] = mx;
    __syncthreads();
    mx = fmaxf(fmaxf(sm[0], sm[1]), fmaxf(sm[2], sm[3]));
  }
  float tau = mx - 1.0f;

  int cnt_prev = -1;
  for (int it = 0; it < 64; ++it) {
    float ls = 0.f, lc = 0.f;
#pragma unroll
    for (int j = 0; j < 16; j++) {
      if (s[j] > tau) { ls += s[j]; lc += 1.f; }
    }
    // 1-barrier phased block reduce (double-buffered broadcast slots)
#pragma unroll
    for (int off = 32; off > 0; off >>= 1) {
      ls += __shfl_down(ls, off, 64);
      lc += __shfl_down(lc, off, 64);
    }
    {
      const int wid = t >> 6;
      float* sb = sm + ((it + 1) & 1) * 8;
      if (lane == 0) { sb[wid * 2] = ls; sb[wid * 2 + 1] = lc; }
      __syncthreads();
      ls = sb[0] + sb[2] + sb[4] + sb[6];
      lc = sb[1] + sb[3] + sb[5] + sb[7];
    }
    const float ntau = (ls - 1.0f) / lc;
    const int ic = (int)lc;
    const bool conv = (ic == cnt_prev);
    tau = ntau;
    cnt_prev = ic;
    if (conv) break;                             // uniform condition
  }

  if (t == 0) s_cnt = 0;
  __syncthreads();

  // write f (vectorized) and compact active pairs into LDS
  float fv[16];
#pragma unroll
  for (int j = 0; j < 16; j++) {
    fv[j] = fmaxf(s[j] - tau, 0.f);
    const bool pred = fv[j] > 0.f;
    const unsigned long long m = __ballot(pred);
    if (m) {
      int bpos = 0;
      if (lane == 0) bpos = atomicAdd(&s_cnt, (int)__popcll(m));
      bpos = __shfl(bpos, 0, 64);
      if (pred) {
        const int pos = bpos + (int)__popcll(m & ((1ull << lane) - 1ull));
        s_idx[pos] = (u16)(base + j);
        s_w[pos] = f2h(fv[j]);
      }
    }
  }
#pragma unroll
  for (int q = 0; q < 4; q++)
    *(float4*)(fo + base + q * 4) = make_float4(fv[q * 4], fv[q * 4 + 1],
                                                fv[q * 4 + 2], fv[q * 4 + 3]);
  __syncthreads();

  const int cnt = s_cnt;
  float4 acc = make_float4(0.f, 0.f, 0.f, 0.f);
  int e = 0;
  for (; e + 4 <= cnt; e += 4) {
    const int m0 = s_idx[e], m1 = s_idx[e + 1], m2 = s_idx[e + 2], m3 = s_idx[e + 3];
    const float w0 = h2f(s_w[e]), w1 = h2f(s_w[e + 1]);
    const float w2 = h2f(s_w[e + 2]), w3 = h2f(s_w[e + 3]);
    const ushort4 a0 = *(const ushort4*)(vh + (size_t)m0 * 1024 + t * 4);
    const ushort4 a1 = *(const ushort4*)(vh + (size_t)m1 * 1024 + t * 4);
    const ushort4 a2 = *(const ushort4*)(vh + (size_t)m2 * 1024 + t * 4);
    const ushort4 a3 = *(const ushort4*)(vh + (size_t)m3 * 1024 + t * 4);
    acc.x += w0 * h2f(a0.x) + w1 * h2f(a1.x) + w2 * h2f(a2.x) + w3 * h2f(a3.x);
    acc.y += w0 * h2f(a0.y) + w1 * h2f(a1.y) + w2 * h2f(a2.y) + w3 * h2f(a3.y);
    acc.z += w0 * h2f(a0.z) + w1 * h2f(a1.z) + w2 * h2f(a2.z) + w3 * h2f(a3.z);
    acc.w += w0 * h2f(a0.w) + w1 * h2f(a1.w) + w2 * h2f(a2.w) + w3 * h2f(a3.w);
  }
  for (; e < cnt; e++) {
    const int m0 = s_idx[e];
    const float w0 = h2f(s_w[e]);
    const ushort4 a0 = *(const ushort4*)(vh + (size_t)m0 * 1024 + t * 4);
    acc.x += w0 * h2f(a0.x); acc.y += w0 * h2f(a0.y);
    acc.z += w0 * h2f(a0.z); acc.w += w0 * h2f(a0.w);
  }
  *(float4*)(xhat + (size_t)row * 1024 + t * 4) = acc;
}

// ================================================================ launch
extern "C" void kernel_launch(void* const* d_in, const int* in_sizes, int n_in,
                              void* d_out, int out_size, void* d_ws, size_t ws_size,
                              hipStream_t stream) {
  const float* x    = (const float*)d_in[0];   // [B, N]
  const float* Wq_w = (const float*)d_in[1];   // [A, N]
  const float* Wq_b = (const float*)d_in[2];   // [A]
  const float* Wk   = (const float*)d_in[3];   // [M, A]
  const float* Wv   = (const float*)d_in[4];   // [M, N]
  const float* gq   = (const float*)d_in[5];
  const float* bq   = (const float*)d_in[6];
  const float* gk   = (const float*)d_in[7];
  const float* bk   = (const float*)d_in[8];
  const float* gv   = (const float*)d_in[9];
  const float* bv   = (const float*)d_in[10];

  float* out = (float*)d_out;
  float* out_x    = out;                                  // B*N
  float* out_xhat = out + (size_t)B_DIM * N_DIM;          // B*N
  float* out_f    = out_xhat + (size_t)B_DIM * N_DIM;     // B*M
  float* out_v    = out_f + (size_t)B_DIM * M_DIM;        // M*N

  // ws layout (fp16 planes), ~136 MB total:
  // xh [B*N], qh [B*A], wqh [A*N], kh [M*A], vh [M*N], sh [B*M], qp [B*A]
  u16* wsu = (u16*)d_ws;
  u16* xh  = wsu;                                    // [B*N]
  u16* qh  = xh + (size_t)B_DIM * N_DIM;             // [B*A]
  u16* wqh = qh + (size_t)B_DIM * A_DIM;             // [A*N]
  u16* kh  = wqh + (size_t)A_DIM * N_DIM;            // [M*A]
  u16* vh  = kh + (size_t)M_DIM * A_DIM;             // [M*N]
  u16* sh  = vh + (size_t)M_DIM * N_DIM;             // [B*M] fp16 scores
  u16* qp  = sh + (size_t)B_DIM * M_DIM;             // [B*A] fp16 q_pre

  // 1) prologue (one dispatch): out_x/xh, wqh, K/V LN
  prep_kernel<<<NB_X + NB_W + NB_KV, 256, 0, stream>>>(
      x, out_x, xh, Wq_w, wqh, Wk, Wv, gk, bk, gv, bv, kh, out_v, vh);

  // 2) q_pre = x @ Wq^T -> fp16 qp
  gemm_mfma<1><<<dim3(A_DIM / 128, B_DIM / 128), 256, 0, stream>>>(
      xh, wqh, qp, A_DIM, N_DIM, N_DIM, N_DIM);
  // 3) q = LN(relu(qp + b)) -> fp16 qh (wave-per-row)
  relu_ln_q_kernel<<<B_DIM / 4, 256, 0, stream>>>(qp, Wq_b, gq, bq, qh);

  // 4) scores = q @ k^T (fp16 hh, single pass) -> fp16 sh
  gemm_mfma<1><<<dim3(M_DIM / 128, B_DIM / 128), 256, 0, stream>>>(
      qh, kh, sh, M_DIM, A_DIM, A_DIM, A_DIM);

  // 5) f = sparsemax(scores/32) + x_hat = f @ v (fp16 gather, fp32 acc)
  sparsemax_xhat_kernel<<<B_DIM, 256, 0, stream>>>(sh, out_f, vh, out_xhat, 0.03125f);
}

// Round 11
// 446.638 us; speedup vs baseline: 1.0124x; 1.0124x over previous
//
#include <hip/hip_runtime.h>

// Problem dims (fixed by the reference)
#define B_DIM 8192
#define N_DIM 1024
#define M_DIM 4096
#define A_DIM 1024
#define LN_EPS 1e-5f

typedef short s8v __attribute__((ext_vector_type(8)));      // 8x16-bit storage
typedef _Float16 h8v __attribute__((ext_vector_type(8)));   // 8 fp16 (4 VGPRs)
typedef float f4v __attribute__((ext_vector_type(4)));      // 4 fp32 acc
typedef unsigned short u16;

// fp32 -> fp16 (RTE). All values in this problem are O(1)-O(30), so fp16's
// 11 mantissa bits beat bf16's 8; range is irrelevant here.
__device__ __forceinline__ u16 f2h(float f) {
  union { _Float16 h; u16 u; } x; x.h = (_Float16)f; return x.u;
}
__device__ __forceinline__ float h2f(u16 u) {
  union { u16 u; _Float16 h; } x; x.u = u; return (float)x.h;
}

// async global->LDS, 16 B per lane. LDS dest = wave-uniform base + lane*16.
__device__ __forceinline__ void glds16(const void* g, void* l) {
  __builtin_amdgcn_global_load_lds(
      (const __attribute__((address_space(1))) unsigned int*)g,
      (__attribute__((address_space(3))) unsigned int*)l, 16, 0, 0);
}

// ---------------- merged prologue (one dispatch, block-uniform branch):
//   blocks [0,4096):    out_x = x ; xh = fp16(x)
//   blocks [4096,4608):  wqh = fp16(Wq)
//   blocks [4608,6656):  k = LN(relu(Wk)) -> kh ; v = LN(relu(Wv)) -> out_v+vh
//                        (wave-per-row, shfl_xor butterfly, no barriers)
#define NB_X 4096
#define NB_W 512
#define NB_KV 2048
__global__ __launch_bounds__(256) void prep_kernel(
    const float* __restrict__ x, float* __restrict__ outx, u16* __restrict__ xh,
    const float* __restrict__ wq, u16* __restrict__ wqh,
    const float* __restrict__ Wk, const float* __restrict__ Wv,
    const float* __restrict__ gk, const float* __restrict__ bk,
    const float* __restrict__ gv, const float* __restrict__ bv,
    u16* __restrict__ kh, float* __restrict__ outv, u16* __restrict__ vh) {
  const int b = blockIdx.x;
  if (b < NB_X + NB_W) {
    const bool isX = b < NB_X;
    const int i = (isX ? b : b - NB_X) * 256 + threadIdx.x;
    const float* src = (isX ? x : wq) + (size_t)i * 8;
    float4 v0 = *(const float4*)src;
    float4 v1 = *(const float4*)(src + 4);
    if (isX) {
      *(float4*)(outx + (size_t)i * 8) = v0;
      *(float4*)(outx + (size_t)i * 8 + 4) = v1;
    }
    const float f[8] = {v0.x, v0.y, v0.z, v0.w, v1.x, v1.y, v1.z, v1.w};
    s8v h;
#pragma unroll
    for (int j = 0; j < 8; j++) h[j] = (short)f2h(f[j]);
    *(s8v*)((isX ? xh : wqh) + (size_t)i * 8) = h;
    return;
  }
  // ---- KV relu+LN, wave-per-row
  const int gw = ((b - NB_X - NB_W) * 256 + threadIdx.x) >> 6;  // 0..8191
  const int l = threadIdx.x & 63;
  const bool isV = gw >= M_DIM;                                 // wave-uniform
  const int row = isV ? gw - M_DIM : gw;
  const float* pin = (isV ? Wv : Wk) + (size_t)row * 1024;
  const float* g = isV ? gv : gk;
  const float* bt = isV ? bv : bk;

  float4 v[4];
  float s = 0.f, ss = 0.f;
#pragma unroll
  for (int j = 0; j < 4; j++) {
    v[j] = *(const float4*)(pin + l * 4 + j * 256);
    v[j].x = fmaxf(v[j].x, 0.f); v[j].y = fmaxf(v[j].y, 0.f);
    v[j].z = fmaxf(v[j].z, 0.f); v[j].w = fmaxf(v[j].w, 0.f);
    s += v[j].x + v[j].y + v[j].z + v[j].w;
    ss += v[j].x * v[j].x + v[j].y * v[j].y + v[j].z * v[j].z + v[j].w * v[j].w;
  }
#pragma unroll
  for (int off = 1; off < 64; off <<= 1) {
    s += __shfl_xor(s, off, 64);
    ss += __shfl_xor(ss, off, 64);
  }
  const float mean = s * (1.f / 1024.f);
  const float var = ss * (1.f / 1024.f) - mean * mean;
  const float rs = rsqrtf(var + LN_EPS);

#pragma unroll
  for (int j = 0; j < 4; j++) {
    const float4 gg = *(const float4*)(g + l * 4 + j * 256);
    const float4 bb = *(const float4*)(bt + l * 4 + j * 256);
    float4 o;
    o.x = (v[j].x - mean) * rs * gg.x + bb.x;
    o.y = (v[j].y - mean) * rs * gg.y + bb.y;
    o.z = (v[j].z - mean) * rs * gg.z + bb.z;
    o.w = (v[j].w - mean) * rs * gg.w + bb.w;
    if (isV)
      *(float4*)(outv + (size_t)row * 1024 + l * 4 + j * 256) = o;
    ushort4 h;
    h.x = f2h(o.x); h.y = f2h(o.y); h.z = f2h(o.z); h.w = f2h(o.w);
    u16* oh = (isV ? vh : kh) + (size_t)row * 1024 + l * 4 + j * 256;
    *(ushort4*)oh = h;
  }
}

// ---------------- wave-per-row relu(+bias)+LN, fp16 input (q path), fp16 out.
__global__ __launch_bounds__(256) void relu_ln_q_kernel(
    const u16* __restrict__ in, const float* __restrict__ bias,
    const float* __restrict__ g, const float* __restrict__ bt,
    u16* __restrict__ outh) {
  const int row = (blockIdx.x * 256 + threadIdx.x) >> 6;
  const int l = threadIdx.x & 63;
  const u16* pin = in + (size_t)row * 1024;

  float e[16];
  float s = 0.f, ss = 0.f;
#pragma unroll
  for (int j = 0; j < 2; j++) {
    const h8v hv = *(const h8v*)(pin + l * 8 + j * 512);
    const float4 b0 = *(const float4*)(bias + l * 8 + j * 512);
    const float4 b1 = *(const float4*)(bias + l * 8 + j * 512 + 4);
    const float bb[8] = {b0.x, b0.y, b0.z, b0.w, b1.x, b1.y, b1.z, b1.w};
#pragma unroll
    for (int k = 0; k < 8; k++) {
      const float z = fmaxf((float)hv[k] + bb[k], 0.f);
      e[j * 8 + k] = z;
      s += z; ss += z * z;
    }
  }
#pragma unroll
  for (int off = 1; off < 64; off <<= 1) {
    s += __shfl_xor(s, off, 64);
    ss += __shfl_xor(ss, off, 64);
  }
  const float mean = s * (1.f / 1024.f);
  const float var = ss * (1.f / 1024.f) - mean * mean;
  const float rs = rsqrtf(var + LN_EPS);

#pragma unroll
  for (int j = 0; j < 2; j++) {
    const float4 g0 = *(const float4*)(g + l * 8 + j * 512);
    const float4 g1 = *(const float4*)(g + l * 8 + j * 512 + 4);
    const float4 t0 = *(const float4*)(bt + l * 8 + j * 512);
    const float4 t1 = *(const float4*)(bt + l * 8 + j * 512 + 4);
    const float gv_[8] = {g0.x, g0.y, g0.z, g0.w, g1.x, g1.y, g1.z, g1.w};
    const float tv[8] = {t0.x, t0.y, t0.z, t0.w, t1.x, t1.y, t1.z, t1.w};
    s8v h;
#pragma unroll
    for (int k = 0; k < 8; k++)
      h[k] = (short)f2h((e[j * 8 + k] - mean) * rs * gv_[k] + tv[k]);
    *(s8v*)(outh + (size_t)row * 1024 + l * 8 + j * 512) = h;
  }
}

// ------------------------------------------------- fp16 MFMA GEMM (nt)
// C[M_,N_] = A[M_,K] * B[N_,K]^T; A,B fp16 planes staged via glds.
// 128x128 tile, BK=64 (two 32-k half-tiles per barrier pair: r9's proven
// structure — 32 MFMA per barrier-drain; r10's 2-phase prefetch regressed
// because __syncthreads drains vmcnt(0), killing the overlap). 4 waves,
// each 64x64 via 4x4 of mfma 16x16x32 f16. OUTH==1: fp16 out; else fp32.
// LDS half-rows: 32 fp16 = 4 chunks of 16 B; chunk c at slot c^((row>>1)&3)
// (2-way bank aliasing on ds_read_b128 = free; glds-compatible). 33 KB LDS.
template <int OUTH>
__global__ __launch_bounds__(256) void gemm_mfma(const u16* __restrict__ AhG,
                                                 const u16* __restrict__ BhG,
                                                 void* __restrict__ Cv,
                                                 int N_, int K, int lda, int ldb) {
  __shared__ __align__(16) u16 Ah[2][128 * 32];
  __shared__ __align__(16) u16 Bh[2][128 * 32];

  const int t = threadIdx.x;
  const int lane = t & 63;
  const int wv = t >> 6;
  const int wm = (wv & 1) * 64;
  const int wn = (wv >> 1) * 64;
  const int m0 = blockIdx.y * 128;
  const int n0 = blockIdx.x * 128;

  // glds lane geometry: within a 16-row chunk, lane covers row=lane>>2, slot=lane&3
  const int ge = lane >> 2;
  const int gg = (lane & 3) ^ ((ge >> 1) & 3);  // global k-chunk to fetch

  // fragment geometry: lane reads row (lane&15), logical chunk (lane>>4)
  const int fr = lane & 15;
  const int fslot = (((lane >> 4) ^ ((fr >> 1) & 3))) * 8;

  f4v acc[4][4];
#pragma unroll
  for (int i = 0; i < 4; i++)
#pragma unroll
    for (int j = 0; j < 4; j++) acc[i][j] = (f4v)(0.f);

  for (int k0 = 0; k0 < K; k0 += 64) {
#pragma unroll
    for (int kh = 0; kh < 2; kh++) {
#pragma unroll
      for (int h = 0; h < 2; h++) {
        const int c = wv * 2 + h;             // chunk 0..7
        const size_t aoff = (size_t)(m0 + c * 16 + ge) * lda + k0 + kh * 32 + gg * 8;
        const size_t boff = (size_t)(n0 + c * 16 + ge) * ldb + k0 + kh * 32 + gg * 8;
        glds16(AhG + aoff, &Ah[kh][c * 512]);
        glds16(BhG + boff, &Bh[kh][c * 512]);
      }
    }
    __syncthreads();

#pragma unroll
    for (int kh = 0; kh < 2; kh++) {
      h8v ah[4], bh[4];
#pragma unroll
      for (int i = 0; i < 4; i++) {
        ah[i] = *(const h8v*)&Ah[kh][(wm + i * 16 + fr) * 32 + fslot];
        bh[i] = *(const h8v*)&Bh[kh][(wn + i * 16 + fr) * 32 + fslot];
      }
#pragma unroll
      for (int i = 0; i < 4; i++)
#pragma unroll
        for (int j = 0; j < 4; j++)
          acc[i][j] = __builtin_amdgcn_mfma_f32_16x16x32_f16(ah[i], bh[j], acc[i][j], 0, 0, 0);
    }
    __syncthreads();
  }

  // epilogue: C/D layout 16x16x32: col = lane&15, row = (lane>>4)*4 + reg
  const int cr = (lane >> 4) * 4;
  const int cc = lane & 15;
#pragma unroll
  for (int i = 0; i < 4; i++)
#pragma unroll
    for (int r = 0; r < 4; r++) {
      const size_t rowoff = (size_t)(m0 + wm + i * 16 + cr + r) * N_ + n0 + wn + cc;
      if constexpr (OUTH) {
        u16* cp = (u16*)Cv + rowoff;
#pragma unroll
        for (int j = 0; j < 4; j++) cp[j * 16] = f2h(acc[i][j][r]);
      } else {
        float* cp = (float*)Cv + rowoff;
#pragma unroll
        for (int j = 0; j < 4; j++) cp[j * 16] = acc[i][j][r];
      }
    }
}

// --------------------------------------- fused sparsemax + sparse x_hat = f @ v
// Exact sparsemax tau via fixed-point iteration tau <- (sum_{s>tau} s - 1)/cnt.
// Any fixed point satisfies sum (s - tau)_+ = 1 exactly (KKT), so it IS the
// reference tau. Init tau0 = max(s) - 1: since tau* >= max-1 (largest f <= 1),
// every iterate's threshold set remains a superset of the true support ->
// ~3-6 iterations. Max element always stays active -> cnt >= 1; cap 64 iters.
// Occupancy: u16 idx + fp16 w compact list -> 16.5 KB LDS -> 8 blocks/CU.
__global__ __launch_bounds__(256) void sparsemax_xhat_kernel(
    const u16* __restrict__ sh,    // [B,4096] fp16 raw scores
    float* __restrict__ fout,      // [B,4096] f output (fp32)
    const u16* __restrict__ vh,    // [4096,1024] fp16 v
    float* __restrict__ xhat,      // [B,1024]
    float scale) {
  __shared__ float sm[16];
  __shared__ u16 s_idx[4096];
  __shared__ u16 s_w[4096];
  __shared__ int s_cnt;
  const int row = blockIdx.x;
  const u16* p = sh + (size_t)row * 4096;
  float* fo = fout + (size_t)row * 4096;
  const int t = threadIdx.x;
  const int lane = t & 63;
  const int base = t * 16;   // 16 contiguous elems per thread (vectorized)

  h8v h0 = *(const h8v*)(p + base);
  h8v h1 = *(const h8v*)(p + base + 8);
  float s[16];
#pragma unroll
  for (int j = 0; j < 8; j++) {
    s[j] = (float)h0[j] * scale;
    s[j + 8] = (float)h1[j] * scale;
  }

  // block max -> tau0 = max - 1
  float mx = s[0];
#pragma unroll
  for (int j = 1; j < 16; j++) mx = fmaxf(mx, s[j]);
  {
#pragma unroll
    for (int off = 32; off > 0; off >>= 1) mx = fmaxf(mx, __shfl_down(mx, off, 64));
    const int wid = t >> 6;
    if (lane == 0) sm[wid] = mx;
    __syncthreads();
    mx = fmaxf(fmaxf(sm[0], sm[1]), fmaxf(sm[2], sm[3]));
  }
  float tau = mx - 1.0f;

  int cnt_prev = -1;
  for (int it = 0; it < 64; ++it) {
    float ls = 0.f, lc = 0.f;
#pragma unroll
    for (int j = 0; j < 16; j++) {
      if (s[j] > tau) { ls += s[j]; lc += 1.f; }
    }
    // 1-barrier phased block reduce (double-buffered broadcast slots)
#pragma unroll
    for (int off = 32; off > 0; off >>= 1) {
      ls += __shfl_down(ls, off, 64);
      lc += __shfl_down(lc, off, 64);
    }
    {
      const int wid = t >> 6;
      float* sb = sm + ((it + 1) & 1) * 8;
      if (lane == 0) { sb[wid * 2] = ls; sb[wid * 2 + 1] = lc; }
      __syncthreads();
      ls = sb[0] + sb[2] + sb[4] + sb[6];
      lc = sb[1] + sb[3] + sb[5] + sb[7];
    }
    const float ntau = (ls - 1.0f) / lc;
    const int ic = (int)lc;
    const bool conv = (ic == cnt_prev);
    tau = ntau;
    cnt_prev = ic;
    if (conv) break;                             // uniform condition
  }

  if (t == 0) s_cnt = 0;
  __syncthreads();

  // write f (vectorized) and compact active pairs into LDS
  float fv[16];
#pragma unroll
  for (int j = 0; j < 16; j++) {
    fv[j] = fmaxf(s[j] - tau, 0.f);
    const bool pred = fv[j] > 0.f;
    const unsigned long long m = __ballot(pred);
    if (m) {
      int bpos = 0;
      if (lane == 0) bpos = atomicAdd(&s_cnt, (int)__popcll(m));
      bpos = __shfl(bpos, 0, 64);
      if (pred) {
        const int pos = bpos + (int)__popcll(m & ((1ull << lane) - 1ull));
        s_idx[pos] = (u16)(base + j);
        s_w[pos] = f2h(fv[j]);
      }
    }
  }
#pragma unroll
  for (int q = 0; q < 4; q++)
    *(float4*)(fo + base + q * 4) = make_float4(fv[q * 4], fv[q * 4 + 1],
                                                fv[q * 4 + 2], fv[q * 4 + 3]);
  __syncthreads();

  const int cnt = s_cnt;
  float4 acc = make_float4(0.f, 0.f, 0.f, 0.f);
  int e = 0;
  for (; e + 4 <= cnt; e += 4) {
    const int m0 = s_idx[e], m1 = s_idx[e + 1], m2 = s_idx[e + 2], m3 = s_idx[e + 3];
    const float w0 = h2f(s_w[e]), w1 = h2f(s_w[e + 1]);
    const float w2 = h2f(s_w[e + 2]), w3 = h2f(s_w[e + 3]);
    const ushort4 a0 = *(const ushort4*)(vh + (size_t)m0 * 1024 + t * 4);
    const ushort4 a1 = *(const ushort4*)(vh + (size_t)m1 * 1024 + t * 4);
    const ushort4 a2 = *(const ushort4*)(vh + (size_t)m2 * 1024 + t * 4);
    const ushort4 a3 = *(const ushort4*)(vh + (size_t)m3 * 1024 + t * 4);
    acc.x += w0 * h2f(a0.x) + w1 * h2f(a1.x) + w2 * h2f(a2.x) + w3 * h2f(a3.x);
    acc.y += w0 * h2f(a0.y) + w1 * h2f(a1.y) + w2 * h2f(a2.y) + w3 * h2f(a3.y);
    acc.z += w0 * h2f(a0.z) + w1 * h2f(a1.z) + w2 * h2f(a2.z) + w3 * h2f(a3.z);
    acc.w += w0 * h2f(a0.w) + w1 * h2f(a1.w) + w2 * h2f(a2.w) + w3 * h2f(a3.w);
  }
  for (; e < cnt; e++) {
    const int m0 = s_idx[e];
    const float w0 = h2f(s_w[e]);
    const ushort4 a0 = *(const ushort4*)(vh + (size_t)m0 * 1024 + t * 4);
    acc.x += w0 * h2f(a0.x); acc.y += w0 * h2f(a0.y);
    acc.z += w0 * h2f(a0.z); acc.w += w0 * h2f(a0.w);
  }
  *(float4*)(xhat + (size_t)row * 1024 + t * 4) = acc;
}

// ================================================================ launch
extern "C" void kernel_launch(void* const* d_in, const int* in_sizes, int n_in,
                              void* d_out, int out_size, void* d_ws, size_t ws_size,
                              hipStream_t stream) {
  const float* x    = (const float*)d_in[0];   // [B, N]
  const float* Wq_w = (const float*)d_in[1];   // [A, N]
  const float* Wq_b = (const float*)d_in[2];   // [A]
  const float* Wk   = (const float*)d_in[3];   // [M, A]
  const float* Wv   = (const float*)d_in[4];   // [M, N]
  const float* gq   = (const float*)d_in[5];
  const float* bq   = (const float*)d_in[6];
  const float* gk   = (const float*)d_in[7];
  const float* bk   = (const float*)d_in[8];
  const float* gv   = (const float*)d_in[9];
  const float* bv   = (const float*)d_in[10];

  float* out = (float*)d_out;
  float* out_x    = out;                                  // B*N
  float* out_xhat = out + (size_t)B_DIM * N_DIM;          // B*N
  float* out_f    = out_xhat + (size_t)B_DIM * N_DIM;     // B*M
  float* out_v    = out_f + (size_t)B_DIM * M_DIM;        // M*N

  // ws layout (fp16 planes), ~136 MB total:
  // xh [B*N], qh [B*A], wqh [A*N], kh [M*A], vh [M*N], sh [B*M], qp [B*A]
  u16* wsu = (u16*)d_ws;
  u16* xh  = wsu;                                    // [B*N]
  u16* qh  = xh + (size_t)B_DIM * N_DIM;             // [B*A]
  u16* wqh = qh + (size_t)B_DIM * A_DIM;             // [A*N]
  u16* kh  = wqh + (size_t)A_DIM * N_DIM;            // [M*A]
  u16* vh  = kh + (size_t)M_DIM * A_DIM;             // [M*N]
  u16* sh  = vh + (size_t)M_DIM * N_DIM;             // [B*M] fp16 scores
  u16* qp  = sh + (size_t)B_DIM * M_DIM;             // [B*A] fp16 q_pre

  // 1) prologue (one dispatch): out_x/xh, wqh, K/V LN
  prep_kernel<<<NB_X + NB_W + NB_KV, 256, 0, stream>>>(
      x, out_x, xh, Wq_w, wqh, Wk, Wv, gk, bk, gv, bv, kh, out_v, vh);

  // 2) q_pre = x @ Wq^T -> fp16 qp
  gemm_mfma<1><<<dim3(A_DIM / 128, B_DIM / 128), 256, 0, stream>>>(
      xh, wqh, qp, A_DIM, N_DIM, N_DIM, N_DIM);
  // 3) q = LN(relu(qp + b)) -> fp16 qh (wave-per-row)
  relu_ln_q_kernel<<<B_DIM / 4, 256, 0, stream>>>(qp, Wq_b, gq, bq, qh);

  // 4) scores = q @ k^T (fp16 hh, single pass) -> fp16 sh
  gemm_mfma<1><<<dim3(M_DIM / 128, B_DIM / 128), 256, 0, stream>>>(
      qh, kh, sh, M_DIM, A_DIM, A_DIM, A_DIM);

  // 5) f = sparsemax(scores/32) + x_hat = f @ v (fp16 gather, fp32 acc)
  sparsemax_xhat_kernel<<<B_DIM, 256, 0, stream>>>(sh, out_f, vh, out_xhat, 0.03125f);
}

// Round 12
// 432.923 us; speedup vs baseline: 1.0445x; 1.0317x over previous
//
#include <hip/hip_runtime.h>

// Problem dims (fixed by the reference)
#define B_DIM 8192
#define N_DIM 1024
#define M_DIM 4096
#define A_DIM 1024
#define LN_EPS 1e-5f

typedef short s8v __attribute__((ext_vector_type(8)));      // 8x16-bit storage
typedef _Float16 h8v __attribute__((ext_vector_type(8)));   // 8 fp16 (4 VGPRs)
typedef float f4v __attribute__((ext_vector_type(4)));      // 4 fp32 acc
typedef unsigned short u16;

// fp32 -> fp16 (RTE). All values in this problem are O(1)-O(30), so fp16's
// 11 mantissa bits beat bf16's 8; range is irrelevant here.
__device__ __forceinline__ u16 f2h(float f) {
  union { _Float16 h; u16 u; } x; x.h = (_Float16)f; return x.u;
}
__device__ __forceinline__ float h2f(u16 u) {
  union { u16 u; _Float16 h; } x; x.u = u; return (float)x.h;
}

// async global->LDS, 16 B per lane. LDS dest = wave-uniform base + lane*16.
__device__ __forceinline__ void glds16(const void* g, void* l) {
  __builtin_amdgcn_global_load_lds(
      (const __attribute__((address_space(1))) unsigned int*)g,
      (__attribute__((address_space(3))) unsigned int*)l, 16, 0, 0);
}

// ---------------- fused: out_x = x ; xh = fp16(x) ; wqh = fp16(Wq) (one grid)
// NOTE (r11 lesson): keep this SEPARATE from the LN kernel — merging them into
// one branchy dispatch throttles the copy blocks to the LN branch's occupancy
// (+12 us regression, r11 vs r9).
__global__ __launch_bounds__(256) void fused_cvt_kernel(
    const float* __restrict__ x, float* __restrict__ outx, u16* __restrict__ xh,
    const float* __restrict__ wq, u16* __restrict__ wqh) {
  const int n8x = B_DIM * N_DIM / 8;   // 1048576
  const int n8w = A_DIM * N_DIM / 8;   // 131072
  int i = blockIdx.x * 256 + threadIdx.x;
  if (i < n8x) {
    const float* src = x + (size_t)i * 8;
    float4 v0 = *(const float4*)src;
    float4 v1 = *(const float4*)(src + 4);
    *(float4*)(outx + (size_t)i * 8) = v0;
    *(float4*)(outx + (size_t)i * 8 + 4) = v1;
    const float f[8] = {v0.x, v0.y, v0.z, v0.w, v1.x, v1.y, v1.z, v1.w};
    s8v h;
#pragma unroll
    for (int j = 0; j < 8; j++) h[j] = (short)f2h(f[j]);
    *(s8v*)(xh + (size_t)i * 8) = h;
  } else if (i < n8x + n8w) {
    const int k = i - n8x;
    const float* src = wq + (size_t)k * 8;
    float4 v0 = *(const float4*)src;
    float4 v1 = *(const float4*)(src + 4);
    const float f[8] = {v0.x, v0.y, v0.z, v0.w, v1.x, v1.y, v1.z, v1.w};
    s8v h;
#pragma unroll
    for (int j = 0; j < 8; j++) h[j] = (short)f2h(f[j]);
    *(s8v*)(wqh + (size_t)k * 8) = h;
  }
}

// ---------------- wave-per-row relu+LN, fp32 input. One dispatch covers the
// K rows (gw < M) and V rows (gw >= M). 6-step shfl_xor butterfly reduce:
// no barriers, no LDS. 4 rows per 256-thread block.
__global__ __launch_bounds__(256) void relu_ln_kv_kernel(
    const float* __restrict__ Wk, const float* __restrict__ Wv,
    const float* __restrict__ gk, const float* __restrict__ bk,
    const float* __restrict__ gv, const float* __restrict__ bv,
    u16* __restrict__ kh, float* __restrict__ outv, u16* __restrict__ vh) {
  const int gw = (blockIdx.x * 256 + threadIdx.x) >> 6;  // global wave id
  const int l = threadIdx.x & 63;
  const bool isV = gw >= M_DIM;                          // wave-uniform
  const int row = isV ? gw - M_DIM : gw;
  const float* pin = (isV ? Wv : Wk) + (size_t)row * 1024;
  const float* g = isV ? gv : gk;
  const float* bt = isV ? bv : bk;

  float4 v[4];
  float s = 0.f, ss = 0.f;
#pragma unroll
  for (int j = 0; j < 4; j++) {
    v[j] = *(const float4*)(pin + l * 4 + j * 256);
    v[j].x = fmaxf(v[j].x, 0.f); v[j].y = fmaxf(v[j].y, 0.f);
    v[j].z = fmaxf(v[j].z, 0.f); v[j].w = fmaxf(v[j].w, 0.f);
    s += v[j].x + v[j].y + v[j].z + v[j].w;
    ss += v[j].x * v[j].x + v[j].y * v[j].y + v[j].z * v[j].z + v[j].w * v[j].w;
  }
#pragma unroll
  for (int off = 1; off < 64; off <<= 1) {
    s += __shfl_xor(s, off, 64);
    ss += __shfl_xor(ss, off, 64);
  }
  const float mean = s * (1.f / 1024.f);
  const float var = ss * (1.f / 1024.f) - mean * mean;
  const float rs = rsqrtf(var + LN_EPS);

#pragma unroll
  for (int j = 0; j < 4; j++) {
    const float4 gg = *(const float4*)(g + l * 4 + j * 256);
    const float4 bb = *(const float4*)(bt + l * 4 + j * 256);
    float4 o;
    o.x = (v[j].x - mean) * rs * gg.x + bb.x;
    o.y = (v[j].y - mean) * rs * gg.y + bb.y;
    o.z = (v[j].z - mean) * rs * gg.z + bb.z;
    o.w = (v[j].w - mean) * rs * gg.w + bb.w;
    if (isV)
      *(float4*)(outv + (size_t)row * 1024 + l * 4 + j * 256) = o;
    ushort4 h;
    h.x = f2h(o.x); h.y = f2h(o.y); h.z = f2h(o.z); h.w = f2h(o.w);
    u16* oh = (isV ? vh : kh) + (size_t)row * 1024 + l * 4 + j * 256;
    *(ushort4*)oh = h;
  }
}

// ---------------- wave-per-row relu(+bias)+LN, fp16 input (q path), fp16 out.
__global__ __launch_bounds__(256) void relu_ln_q_kernel(
    const u16* __restrict__ in, const float* __restrict__ bias,
    const float* __restrict__ g, const float* __restrict__ bt,
    u16* __restrict__ outh) {
  const int row = (blockIdx.x * 256 + threadIdx.x) >> 6;
  const int l = threadIdx.x & 63;
  const u16* pin = in + (size_t)row * 1024;

  float e[16];
  float s = 0.f, ss = 0.f;
#pragma unroll
  for (int j = 0; j < 2; j++) {
    const h8v hv = *(const h8v*)(pin + l * 8 + j * 512);
    const float4 b0 = *(const float4*)(bias + l * 8 + j * 512);
    const float4 b1 = *(const float4*)(bias + l * 8 + j * 512 + 4);
    const float bb[8] = {b0.x, b0.y, b0.z, b0.w, b1.x, b1.y, b1.z, b1.w};
#pragma unroll
    for (int k = 0; k < 8; k++) {
      const float z = fmaxf((float)hv[k] + bb[k], 0.f);
      e[j * 8 + k] = z;
      s += z; ss += z * z;
    }
  }
#pragma unroll
  for (int off = 1; off < 64; off <<= 1) {
    s += __shfl_xor(s, off, 64);
    ss += __shfl_xor(ss, off, 64);
  }
  const float mean = s * (1.f / 1024.f);
  const float var = ss * (1.f / 1024.f) - mean * mean;
  const float rs = rsqrtf(var + LN_EPS);

#pragma unroll
  for (int j = 0; j < 2; j++) {
    const float4 g0 = *(const float4*)(g + l * 8 + j * 512);
    const float4 g1 = *(const float4*)(g + l * 8 + j * 512 + 4);
    const float4 t0 = *(const float4*)(bt + l * 8 + j * 512);
    const float4 t1 = *(const float4*)(bt + l * 8 + j * 512 + 4);
    const float gv_[8] = {g0.x, g0.y, g0.z, g0.w, g1.x, g1.y, g1.z, g1.w};
    const float tv[8] = {t0.x, t0.y, t0.z, t0.w, t1.x, t1.y, t1.z, t1.w};
    s8v h;
#pragma unroll
    for (int k = 0; k < 8; k++)
      h[k] = (short)f2h((e[j * 8 + k] - mean) * rs * gv_[k] + tv[k]);
    *(s8v*)(outh + (size_t)row * 1024 + l * 8 + j * 512) = h;
  }
}

// ------------------------------------------------- fp16 MFMA GEMM (nt)
// C[M_,N_] = A[M_,K] * B[N_,K]^T; A,B fp16 planes staged via glds.
// 128x128 tile, BK=64 (two 32-k half-tiles per barrier pair: halves the
// per-iteration fixed cost of 2 barriers + vmcnt(0) drain; each half's LDS
// layout is byte-identical to the proven BK=32 layout). 4 waves, each 64x64
// via 4x4 of mfma 16x16x32 f16. OUTH==1: fp16 out (intermediate); else fp32.
// LDS half-rows: 32 fp16 = 4 chunks of 16 B; chunk c at slot c^((row>>1)&3)
// (2-way bank aliasing on ds_read_b128 = free; glds-compatible). 33 KB LDS.
template <int OUTH>
__global__ __launch_bounds__(256) void gemm_mfma(const u16* __restrict__ AhG,
                                                 const u16* __restrict__ BhG,
                                                 void* __restrict__ Cv,
                                                 int N_, int K, int lda, int ldb) {
  __shared__ __align__(16) u16 Ah[2][128 * 32];
  __shared__ __align__(16) u16 Bh[2][128 * 32];

  const int t = threadIdx.x;
  const int lane = t & 63;
  const int wv = t >> 6;
  const int wm = (wv & 1) * 64;
  const int wn = (wv >> 1) * 64;
  const int m0 = blockIdx.y * 128;
  const int n0 = blockIdx.x * 128;

  // glds lane geometry: within a 16-row chunk, lane covers row=lane>>2, slot=lane&3
  const int ge = lane >> 2;
  const int gg = (lane & 3) ^ ((ge >> 1) & 3);  // global k-chunk to fetch

  // fragment geometry: lane reads row (lane&15), logical chunk (lane>>4)
  const int fr = lane & 15;
  const int fslot = (((lane >> 4) ^ ((fr >> 1) & 3))) * 8;

  f4v acc[4][4];
#pragma unroll
  for (int i = 0; i < 4; i++)
#pragma unroll
    for (int j = 0; j < 4; j++) acc[i][j] = (f4v)(0.f);

  for (int k0 = 0; k0 < K; k0 += 64) {
#pragma unroll
    for (int kh = 0; kh < 2; kh++) {
#pragma unroll
      for (int h = 0; h < 2; h++) {
        const int c = wv * 2 + h;             // chunk 0..7
        const size_t aoff = (size_t)(m0 + c * 16 + ge) * lda + k0 + kh * 32 + gg * 8;
        const size_t boff = (size_t)(n0 + c * 16 + ge) * ldb + k0 + kh * 32 + gg * 8;
        glds16(AhG + aoff, &Ah[kh][c * 512]);
        glds16(BhG + boff, &Bh[kh][c * 512]);
      }
    }
    __syncthreads();

#pragma unroll
    for (int kh = 0; kh < 2; kh++) {
      h8v ah[4], bh[4];
#pragma unroll
      for (int i = 0; i < 4; i++) {
        ah[i] = *(const h8v*)&Ah[kh][(wm + i * 16 + fr) * 32 + fslot];
        bh[i] = *(const h8v*)&Bh[kh][(wn + i * 16 + fr) * 32 + fslot];
      }
#pragma unroll
      for (int i = 0; i < 4; i++)
#pragma unroll
        for (int j = 0; j < 4; j++)
          acc[i][j] = __builtin_amdgcn_mfma_f32_16x16x32_f16(ah[i], bh[j], acc[i][j], 0, 0, 0);
    }
    __syncthreads();
  }

  // epilogue: C/D layout 16x16x32: col = lane&15, row = (lane>>4)*4 + reg
  const int cr = (lane >> 4) * 4;
  const int cc = lane & 15;
#pragma unroll
  for (int i = 0; i < 4; i++)
#pragma unroll
    for (int r = 0; r < 4; r++) {
      const size_t rowoff = (size_t)(m0 + wm + i * 16 + cr + r) * N_ + n0 + wn + cc;
      if constexpr (OUTH) {
        u16* cp = (u16*)Cv + rowoff;
#pragma unroll
        for (int j = 0; j < 4; j++) cp[j * 16] = f2h(acc[i][j][r]);
      } else {
        float* cp = (float*)Cv + rowoff;
#pragma unroll
        for (int j = 0; j < 4; j++) cp[j * 16] = acc[i][j][r];
      }
    }
}

// --------------------------------------- fused sparsemax + sparse x_hat = f @ v
// Exact sparsemax tau via fixed-point iteration tau <- (sum_{s>tau} s - 1)/cnt.
// Any fixed point satisfies sum (s - tau)_+ = 1 exactly (KKT), so it IS the
// reference tau. Init tau0 = max(s) - 1: since tau* >= max-1 (largest f <= 1),
// every iterate's threshold set remains a superset of the true support ->
// ~3-6 iterations. Max element always stays active -> cnt >= 1; cap 64 iters.
// Occupancy: u16 idx + fp16 w compact list -> 16.5 KB LDS -> 8 blocks/CU.
__global__ __launch_bounds__(256) void sparsemax_xhat_kernel(
    const u16* __restrict__ sh,    // [B,4096] fp16 raw scores
    float* __restrict__ fout,      // [B,4096] f output (fp32)
    const u16* __restrict__ vh,    // [4096,1024] fp16 v
    float* __restrict__ xhat,      // [B,1024]
    float scale) {
  __shared__ float sm[16];
  __shared__ u16 s_idx[4096];
  __shared__ u16 s_w[4096];
  __shared__ int s_cnt;
  const int row = blockIdx.x;
  const u16* p = sh + (size_t)row * 4096;
  float* fo = fout + (size_t)row * 4096;
  const int t = threadIdx.x;
  const int lane = t & 63;
  const int base = t * 16;   // 16 contiguous elems per thread (vectorized)

  h8v h0 = *(const h8v*)(p + base);
  h8v h1 = *(const h8v*)(p + base + 8);
  float s[16];
#pragma unroll
  for (int j = 0; j < 8; j++) {
    s[j] = (float)h0[j] * scale;
    s[j + 8] = (float)h1[j] * scale;
  }

  // block max -> tau0 = max - 1
  float mx = s[0];
#pragma unroll
  for (int j = 1; j < 16; j++) mx = fmaxf(mx, s[j]);
  {
#pragma unroll
    for (int off = 32; off > 0; off >>= 1) mx = fmaxf(mx, __shfl_down(mx, off, 64));
    const int wid = t >> 6;
    if (lane == 0) sm[wid] = mx;
    __syncthreads();
    mx = fmaxf(fmaxf(sm[0], sm[1]), fmaxf(sm[2], sm[3]));
  }
  float tau = mx - 1.0f;

  int cnt_prev = -1;
  for (int it = 0; it < 64; ++it) {
    float ls = 0.f, lc = 0.f;
#pragma unroll
    for (int j = 0; j < 16; j++) {
      if (s[j] > tau) { ls += s[j]; lc += 1.f; }
    }
    // 1-barrier phased block reduce (double-buffered broadcast slots)
#pragma unroll
    for (int off = 32; off > 0; off >>= 1) {
      ls += __shfl_down(ls, off, 64);
      lc += __shfl_down(lc, off, 64);
    }
    {
      const int wid = t >> 6;
      float* sb = sm + ((it + 1) & 1) * 8;
      if (lane == 0) { sb[wid * 2] = ls; sb[wid * 2 + 1] = lc; }
      __syncthreads();
      ls = sb[0] + sb[2] + sb[4] + sb[6];
      lc = sb[1] + sb[3] + sb[5] + sb[7];
    }
    const float ntau = (ls - 1.0f) / lc;
    const int ic = (int)lc;
    const bool conv = (ic == cnt_prev);
    tau = ntau;
    cnt_prev = ic;
    if (conv) break;                             // uniform condition
  }

  if (t == 0) s_cnt = 0;
  __syncthreads();

  // write f (vectorized) and compact active pairs into LDS
  float fv[16];
#pragma unroll
  for (int j = 0; j < 16; j++) {
    fv[j] = fmaxf(s[j] - tau, 0.f);
    const bool pred = fv[j] > 0.f;
    const unsigned long long m = __ballot(pred);
    if (m) {
      int bpos = 0;
      if (lane == 0) bpos = atomicAdd(&s_cnt, (int)__popcll(m));
      bpos = __shfl(bpos, 0, 64);
      if (pred) {
        const int pos = bpos + (int)__popcll(m & ((1ull << lane) - 1ull));
        s_idx[pos] = (u16)(base + j);
        s_w[pos] = f2h(fv[j]);
      }
    }
  }
#pragma unroll
  for (int q = 0; q < 4; q++)
    *(float4*)(fo + base + q * 4) = make_float4(fv[q * 4], fv[q * 4 + 1],
                                                fv[q * 4 + 2], fv[q * 4 + 3]);
  __syncthreads();

  const int cnt = s_cnt;
  float4 acc = make_float4(0.f, 0.f, 0.f, 0.f);
  int e = 0;
  for (; e + 4 <= cnt; e += 4) {
    const int m0 = s_idx[e], m1 = s_idx[e + 1], m2 = s_idx[e + 2], m3 = s_idx[e + 3];
    const float w0 = h2f(s_w[e]), w1 = h2f(s_w[e + 1]);
    const float w2 = h2f(s_w[e + 2]), w3 = h2f(s_w[e + 3]);
    const ushort4 a0 = *(const ushort4*)(vh + (size_t)m0 * 1024 + t * 4);
    const ushort4 a1 = *(const ushort4*)(vh + (size_t)m1 * 1024 + t * 4);
    const ushort4 a2 = *(const ushort4*)(vh + (size_t)m2 * 1024 + t * 4);
    const ushort4 a3 = *(const ushort4*)(vh + (size_t)m3 * 1024 + t * 4);
    acc.x += w0 * h2f(a0.x) + w1 * h2f(a1.x) + w2 * h2f(a2.x) + w3 * h2f(a3.x);
    acc.y += w0 * h2f(a0.y) + w1 * h2f(a1.y) + w2 * h2f(a2.y) + w3 * h2f(a3.y);
    acc.z += w0 * h2f(a0.z) + w1 * h2f(a1.z) + w2 * h2f(a2.z) + w3 * h2f(a3.z);
    acc.w += w0 * h2f(a0.w) + w1 * h2f(a1.w) + w2 * h2f(a2.w) + w3 * h2f(a3.w);
  }
  for (; e < cnt; e++) {
    const int m0 = s_idx[e];
    const float w0 = h2f(s_w[e]);
    const ushort4 a0 = *(const ushort4*)(vh + (size_t)m0 * 1024 + t * 4);
    acc.x += w0 * h2f(a0.x); acc.y += w0 * h2f(a0.y);
    acc.z += w0 * h2f(a0.z); acc.w += w0 * h2f(a0.w);
  }
  *(float4*)(xhat + (size_t)row * 1024 + t * 4) = acc;
}

// ================================================================ launch
extern "C" void kernel_launch(void* const* d_in, const int* in_sizes, int n_in,
                              void* d_out, int out_size, void* d_ws, size_t ws_size,
                              hipStream_t stream) {
  const float* x    = (const float*)d_in[0];   // [B, N]
  const float* Wq_w = (const float*)d_in[1];   // [A, N]
  const float* Wq_b = (const float*)d_in[2];   // [A]
  const float* Wk   = (const float*)d_in[3];   // [M, A]
  const float* Wv   = (const float*)d_in[4];   // [M, N]
  const float* gq   = (const float*)d_in[5];
  const float* bq   = (const float*)d_in[6];
  const float* gk   = (const float*)d_in[7];
  const float* bk   = (const float*)d_in[8];
  const float* gv   = (const float*)d_in[9];
  const float* bv   = (const float*)d_in[10];

  float* out = (float*)d_out;
  float* out_x    = out;                                  // B*N
  float* out_xhat = out + (size_t)B_DIM * N_DIM;          // B*N
  float* out_f    = out_xhat + (size_t)B_DIM * N_DIM;     // B*M
  float* out_v    = out_f + (size_t)B_DIM * M_DIM;        // M*N

  // ws layout (fp16 planes), ~136 MB total:
  // xh [B*N], qh [B*A], wqh [A*N], kh [M*A], vh [M*N], sh [B*M], qp [B*A]
  u16* wsu = (u16*)d_ws;
  u16* xh  = wsu;                                    // [B*N]
  u16* qh  = xh + (size_t)B_DIM * N_DIM;             // [B*A]
  u16* wqh = qh + (size_t)B_DIM * A_DIM;             // [A*N]
  u16* kh  = wqh + (size_t)A_DIM * N_DIM;            // [M*A]
  u16* vh  = kh + (size_t)M_DIM * A_DIM;             // [M*N]
  u16* sh  = vh + (size_t)M_DIM * N_DIM;             // [B*M] fp16 scores
  u16* qp  = sh + (size_t)B_DIM * M_DIM;             // [B*A] fp16 q_pre

  // 1) out_x = x ; xh = fp16(x) ; wqh = fp16(Wq_w)   (one dispatch)
  fused_cvt_kernel<<<(B_DIM * N_DIM / 8 + A_DIM * N_DIM / 8) / 256, 256, 0, stream>>>(
      x, out_x, xh, Wq_w, wqh);
  // 2) k = LN(relu(Wk)) -> kh ; v = LN(relu(Wv)) -> out_v + vh  (one dispatch,
  //    wave-per-row, no barriers)
  relu_ln_kv_kernel<<<(2 * M_DIM) / 4, 256, 0, stream>>>(
      Wk, Wv, gk, bk, gv, bv, kh, out_v, vh);

  // 3) q_pre = x @ Wq^T -> fp16 qp
  gemm_mfma<1><<<dim3(A_DIM / 128, B_DIM / 128), 256, 0, stream>>>(
      xh, wqh, qp, A_DIM, N_DIM, N_DIM, N_DIM);
  // 4) q = LN(relu(qp + b)) -> fp16 qh (wave-per-row)
  relu_ln_q_kernel<<<B_DIM / 4, 256, 0, stream>>>(qp, Wq_b, gq, bq, qh);

  // 5) scores = q @ k^T (fp16 hh, single pass) -> fp16 sh
  gemm_mfma<1><<<dim3(M_DIM / 128, B_DIM / 128), 256, 0, stream>>>(
      qh, kh, sh, M_DIM, A_DIM, A_DIM, A_DIM);

  // 6) f = sparsemax(scores/32) + x_hat = f @ v (fp16 gather, fp32 acc)
  sparsemax_xhat_kernel<<<B_DIM, 256, 0, stream>>>(sh, out_f, vh, out_xhat, 0.03125f);
}